// Round 1
// baseline (138.178 us; speedup 1.0000x reference)
//
#include <hip/hip_runtime.h>

typedef float f4 __attribute__((ext_vector_type(4)));

#define N 1536
#define D 768
#define H 64
#define NN (N * N)

// ---------------------------------------------------------------------------
// Kernel 1: A[i,h] = (E @ W1a)[i,h] + b1[h] - p_i.Wp[h] - v_i.Wv[h]
//           B[j,h] = (E @ W1b)[j,h]        + p_j.Wp[h] + v_j.Wv[h]
// Split-K partials written to P[kc][h2][i]  (h2 in [0,128): 0..63=A, 64..127=B)
// Bias + geometry terms folded into partial kc==0.
// ---------------------------------------------------------------------------
__global__ __launch_bounds__(256) void k1_gemm(
    const float* __restrict__ E, const float* __restrict__ pos,
    const float* __restrict__ ppos, const float* __restrict__ W1,
    const float* __restrict__ b1, float* __restrict__ P, int KC)
{
    __shared__ f4 Es[16][192];  // supports KC up to 768 (16 rows x 768 f32)

    const int tid = threadIdx.x;
    const int i0  = blockIdx.x * 16;
    const int kcc = blockIdx.y;
    const int k0  = kcc * KC;
    const int kd4 = KC >> 2;

    // stage E[i0..i0+15][k0..k0+KC) into LDS (coalesced f4 loads)
    for (int f = tid; f < 16 * kd4; f += 256) {
        int row = f / kd4;
        int c   = f - row * kd4;
        Es[row][c] = *(const f4*)&E[(size_t)(i0 + row) * D + k0 + c * 4];
    }
    __syncthreads();

    const int h2  = tid & 127;
    const int ig  = tid >> 7;       // 0 -> rows 0..7, 1 -> rows 8..15
    const int mat = h2 >> 6;        // 0 = A (W1[0:768]), 1 = B (W1[768:1536])
    const int h   = h2 & 63;
    const float* Wcol = W1 + (size_t)(mat * D + k0) * H + h;

    float acc[8] = {0.f, 0.f, 0.f, 0.f, 0.f, 0.f, 0.f, 0.f};

    for (int kk = 0; kk < KC; kk += 4) {
        float w0 = Wcol[(size_t)(kk + 0) * H];
        float w1 = Wcol[(size_t)(kk + 1) * H];
        float w2 = Wcol[(size_t)(kk + 2) * H];
        float w3 = Wcol[(size_t)(kk + 3) * H];
#pragma unroll
        for (int r = 0; r < 8; ++r) {
            f4 e = Es[ig * 8 + r][kk >> 2];
            acc[r] = fmaf(e.x, w0, acc[r]);
            acc[r] = fmaf(e.y, w1, acc[r]);
            acc[r] = fmaf(e.z, w2, acc[r]);
            acc[r] = fmaf(e.w, w3, acc[r]);
        }
    }

    if (kcc == 0) {
        // Wp = W1s rows 0..2 (row 7, the vdiff row, folds into row 1 since vdiff = rel_pos.y)
        float wp0 = W1[(size_t)(2 * D + 0) * H + h];
        float wp1 = W1[(size_t)(2 * D + 1) * H + h] + W1[(size_t)(2 * D + 7) * H + h];
        float wp2 = W1[(size_t)(2 * D + 2) * H + h];
        float wv0 = W1[(size_t)(2 * D + 4) * H + h];
        float wv1 = W1[(size_t)(2 * D + 5) * H + h];
        float wv2 = W1[(size_t)(2 * D + 6) * H + h];
        float bb  = b1[h];
#pragma unroll
        for (int r = 0; r < 8; ++r) {
            int i = i0 + ig * 8 + r;
            float px = pos[3 * i], py = pos[3 * i + 1], pz = pos[3 * i + 2];
            float vx = px - ppos[3 * i];
            float vy = py - ppos[3 * i + 1];
            float vz = pz - ppos[3 * i + 2];
            float g = px * wp0 + py * wp1 + pz * wp2 + vx * wv0 + vy * wv1 + vz * wv2;
            acc[r] += (mat == 0) ? (bb - g) : g;
        }
    }

#pragma unroll
    for (int r = 0; r < 8; ++r) {
        int i = i0 + ig * 8 + r;
        P[(size_t)(kcc * 128 + h2) * N + i] = acc[r];
    }
}

// ---------------------------------------------------------------------------
// Kernel 2: 64x64 pair tile per block, 4x4 pairs per thread.
// preact[h] = A[i,h] + B[j,h] + dist*w3[h];  hidden = relu(preact)
// logits = hidden @ W2 + b2;  softmax max/argmax; classification rules.
// ---------------------------------------------------------------------------
__global__ __launch_bounds__(256) void k2_main(
    const float* __restrict__ P, int nkc,
    const float* __restrict__ W1, const float* __restrict__ W2,
    const float* __restrict__ b2, const float* __restrict__ pos,
    const float* __restrict__ ppos, float* __restrict__ out)
{
    __shared__ f4 As[64][16];     // [h][i_local/4]
    __shared__ f4 Bs[64][16];     // [h][j_local/4]
    __shared__ float w3s[64];
    __shared__ f4 W2s[64];
    __shared__ float pis[64][3], vis[64][3], pjs[64][3], vjs[64][3];

    const int tid = threadIdx.x;
    const int i0 = blockIdx.y * 64;
    const int j0 = blockIdx.x * 64;

    // stage A/B tiles (sum split-K partials)
    for (int g = 0; g < 4; ++g) {
        int f = g * 256 + tid;       // 0..1023
        int h = f >> 4;
        int c = f & 15;
        f4 sa = {0.f, 0.f, 0.f, 0.f};
        f4 sb = {0.f, 0.f, 0.f, 0.f};
        for (int kc = 0; kc < nkc; ++kc) {
            sa += *(const f4*)&P[(size_t)(kc * 128 + h) * N + i0 + c * 4];
            sb += *(const f4*)&P[(size_t)(kc * 128 + 64 + h) * N + j0 + c * 4];
        }
        As[h][c] = sa;
        Bs[h][c] = sb;
    }
    if (tid < 64) {
        w3s[tid] = W1[(size_t)(2 * D + 3) * H + tid];
        W2s[tid] = *(const f4*)&W2[tid * 4];
        int i = i0 + tid;
        float px = pos[3 * i], py = pos[3 * i + 1], pz = pos[3 * i + 2];
        pis[tid][0] = px; pis[tid][1] = py; pis[tid][2] = pz;
        vis[tid][0] = px - ppos[3 * i];
        vis[tid][1] = py - ppos[3 * i + 1];
        vis[tid][2] = pz - ppos[3 * i + 2];
    } else if (tid < 128) {
        int t = tid - 64;
        int j = j0 + t;
        float px = pos[3 * j], py = pos[3 * j + 1], pz = pos[3 * j + 2];
        pjs[t][0] = px; pjs[t][1] = py; pjs[t][2] = pz;
        vjs[t][0] = px - ppos[3 * j];
        vjs[t][1] = py - ppos[3 * j + 1];
        vjs[t][2] = pz - ppos[3 * j + 2];
    }
    __syncthreads();

    const int tx = tid & 15;   // j sub-tile
    const int ty = tid >> 4;   // i sub-tile

    // pair distances (numpy order, no fma contraction: sensitive thresholds)
    float dist[16];
    {
#pragma clang fp contract(off)
#pragma unroll
        for (int a = 0; a < 4; ++a) {
#pragma unroll
            for (int b = 0; b < 4; ++b) {
                int il = ty * 4 + a, jl = tx * 4 + b;
                float dx = pjs[jl][0] - pis[il][0];
                float dy = pjs[jl][1] - pis[il][1];
                float dz = pjs[jl][2] - pis[il][2];
                float s = dx * dx;
                s = s + dy * dy;
                s = s + dz * dz;
                dist[a * 4 + b] = sqrtf(s);
            }
        }
    }

    f4 acc[16];
#pragma unroll
    for (int q = 0; q < 16; ++q) acc[q] = (f4){0.f, 0.f, 0.f, 0.f};

#pragma unroll 8
    for (int h = 0; h < 64; ++h) {
        f4 A4 = As[h][ty];
        f4 B4 = Bs[h][tx];
        float w3h = w3s[h];
        f4 w2r = W2s[h];
#pragma unroll
        for (int a = 0; a < 4; ++a) {
#pragma unroll
            for (int b = 0; b < 4; ++b) {
                float hid = fmaf(dist[a * 4 + b], w3h, A4[a] + B4[b]);
                hid = fmaxf(hid, 0.f);
                acc[a * 4 + b] += hid * w2r;
            }
        }
    }

    const f4 b2v = *(const f4*)b2;

#pragma unroll
    for (int a = 0; a < 4; ++a) {
        int i = i0 + ty * 4 + a;
        f4 rt4, cf4, vl4;
#pragma unroll
        for (int b = 0; b < 4; ++b) {
            int j = j0 + tx * 4 + b;
            int il = ty * 4 + a, jl = tx * 4 + b;
            float dd = dist[a * 4 + b];
            float dy, closing;
            {
#pragma clang fp contract(off)
                float dx = pjs[jl][0] - pis[il][0];
                dy       = pjs[jl][1] - pis[il][1];
                float dz = pjs[jl][2] - pis[il][2];
                float rvx = vjs[jl][0] - vis[il][0];
                float rvy = vjs[jl][1] - vis[il][1];
                float rvz = vjs[jl][2] - vis[il][2];
                float dot = dx * rvx;
                dot = dot + dy * rvy;
                dot = dot + dz * rvz;
                closing = -dot / fmaxf(dd, 1e-6f);
            }
            f4 l = acc[a * 4 + b] + b2v;
            // argmax over logits == argmax over probs (softmax monotone), first-max
            float mx = l.x; int bidx = 0;
            if (l.y > mx) { mx = l.y; bidx = 1; }
            if (l.z > mx) { mx = l.z; bidx = 2; }
            if (l.w > mx) { mx = l.w; bidx = 3; }
            float s = expf(l.x - mx);
            s += expf(l.y - mx);
            s += expf(l.z - mx);
            s += expf(l.w - mx);
            float conf = 1.0f / s;   // == max(softmax(l))

            bool near = dd < 0.25f;
            bool appr = !near && (closing > 0.05f);
            bool flee = !near && !appr && (closing < -0.05f);
            bool above = !near && !appr && !flee && (fabsf(dy) > 0.3f) && (dd < 0.5f);
            int rt = near ? 0 : appr ? 1 : flee ? 2 : above ? 3 : bidx;
            float co = near  ? fmaxf(conf, 0.8f)
                     : appr  ? fmaxf(conf, 0.6f)
                     : flee  ? fmaxf(conf, 0.6f)
                     : above ? fmaxf(conf, 0.5f)
                             : conf;
            float vd = ((j > i) && (co > 0.3f)) ? 1.0f : 0.0f;
            rt4[b] = (float)rt;
            cf4[b] = co;
            vl4[b] = vd;
        }
        int col = j0 + tx * 4;
        *(f4*)&out[(size_t)i * N + col]            = rt4;
        *(f4*)&out[(size_t)NN + (size_t)i * N + col]  = cf4;
        *(f4*)&out[(size_t)2 * NN + (size_t)i * N + col] = vl4;
    }
}

extern "C" void kernel_launch(void* const* d_in, const int* in_sizes, int n_in,
                              void* d_out, int out_size, void* d_ws, size_t ws_size,
                              hipStream_t stream)
{
    const float* E    = (const float*)d_in[0];   // N x 768
    const float* pos  = (const float*)d_in[1];   // N x 3
    const float* ppos = (const float*)d_in[2];   // N x 3
    const float* W1   = (const float*)d_in[3];   // 1544 x 64
    const float* b1   = (const float*)d_in[4];   // 64
    const float* W2   = (const float*)d_in[5];   // 64 x 4
    const float* b2   = (const float*)d_in[6];   // 4
    float* out = (float*)d_out;
    float* P   = (float*)d_ws;

    int nkc = (ws_size >= (size_t)4 * 128 * N * 4) ? 4 : 1;
    int KC  = D / nkc;

    dim3 g1(N / 16, nkc);
    k1_gemm<<<g1, 256, 0, stream>>>(E, pos, ppos, W1, b1, P, KC);

    dim3 g2(N / 64, N / 64);
    k2_main<<<g2, 256, 0, stream>>>(P, nkc, W1, W2, b2, pos, ppos, out);
}

// Round 2
// 130.162 us; speedup vs baseline: 1.0616x; 1.0616x over previous
//
#include <hip/hip_runtime.h>

typedef float f4 __attribute__((ext_vector_type(4)));
typedef float f2 __attribute__((ext_vector_type(2)));

#define N 1536
#define D 768
#define H 64
#define NN (N * N)

// ---------------------------------------------------------------------------
// Kernel 1: A[i,h] = (E @ W1a)[i,h] + b1[h] - p_i.Wp[h] - v_i.Wv[h]
//           B[j,h] = (E @ W1b)[j,h]        + p_j.Wp[h] + v_j.Wv[h]
// P[kc][h2][i], h2 in [0,128): 0..63 = A, 64..127 = B.
// Each thread: 2 rows x 4 consecutive h-cols -> f4 W loads (coalesced),
// E broadcast from LDS, f4 accumulators (v_pk_fma_f32).
// ---------------------------------------------------------------------------
__global__ __launch_bounds__(256) void k1_gemm(
    const float* __restrict__ E, const float* __restrict__ pos,
    const float* __restrict__ ppos, const float* __restrict__ W1,
    const float* __restrict__ b1, float* __restrict__ P, int KC)
{
    __shared__ float Es[16][192];   // one 192-wide K chunk of 16 rows

    const int tid = threadIdx.x;
    const int i0  = blockIdx.x * 16;
    const int kcc = blockIdx.y;
    const int k0  = kcc * KC;

    const int hg  = tid & 31;       // h-group
    const int h0  = hg * 4;         // 0..127 (A: 0..63, B: 64..127)
    const int mat = h0 >> 6;
    const int hc  = h0 & 63;
    const int rp  = tid >> 5;       // 0..7 -> rows 2rp, 2rp+1
    const float* Wbase = W1 + (size_t)(mat * D + k0) * H + hc;

    f4 acc0 = {0.f, 0.f, 0.f, 0.f};
    f4 acc1 = {0.f, 0.f, 0.f, 0.f};

    for (int ks = 0; ks < KC; ks += 192) {
        if (ks) __syncthreads();
        // stage E[i0..i0+15][k0+ks .. +192) : 768 f4 loads, 3 per thread
        for (int f = tid; f < 16 * 48; f += 256) {
            int row = f / 48, c = f - row * 48;
            *(f4*)&Es[row][c * 4] =
                *(const f4*)&E[(size_t)(i0 + row) * D + k0 + ks + c * 4];
        }
        __syncthreads();

        const float* Wc  = Wbase + (size_t)ks * H;
        const float* e0p = Es[2 * rp];
        const float* e1p = Es[2 * rp + 1];
        for (int kk = 0; kk < 192; kk += 8) {
#pragma unroll
            for (int u = 0; u < 8; ++u) {
                f4 w = *(const f4*)&Wc[(size_t)(kk + u) * H];
                float e0 = e0p[kk + u], e1 = e1p[kk + u];
                acc0 = __builtin_elementwise_fma((f4){e0, e0, e0, e0}, w, acc0);
                acc1 = __builtin_elementwise_fma((f4){e1, e1, e1, e1}, w, acc1);
            }
        }
    }

    if (kcc == 0) {
        const float* Ws = W1 + (size_t)2 * D * H + hc;
        f4 wp0 = *(const f4*)&Ws[0 * H];
        f4 wp1 = *(const f4*)&Ws[1 * H] + *(const f4*)&Ws[7 * H]; // vdiff fold
        f4 wp2 = *(const f4*)&Ws[2 * H];
        f4 wv0 = *(const f4*)&Ws[4 * H];
        f4 wv1 = *(const f4*)&Ws[5 * H];
        f4 wv2 = *(const f4*)&Ws[6 * H];
        f4 bb  = *(const f4*)&b1[hc];
#pragma unroll
        for (int r = 0; r < 2; ++r) {
            int i = i0 + 2 * rp + r;
            float px = pos[3 * i], py = pos[3 * i + 1], pz = pos[3 * i + 2];
            float vx = px - ppos[3 * i];
            float vy = py - ppos[3 * i + 1];
            float vz = pz - ppos[3 * i + 2];
            f4 g = px * wp0 + py * wp1 + pz * wp2 + vx * wv0 + vy * wv1 + vz * wv2;
            f4 add = (mat == 0) ? (bb - g) : g;
            if (r == 0) acc0 += add; else acc1 += add;
        }
    }

#pragma unroll
    for (int r = 0; r < 2; ++r) {
        int i = i0 + 2 * rp + r;
        f4 a = r ? acc1 : acc0;
#pragma unroll
        for (int c = 0; c < 4; ++c)
            P[(size_t)(kcc * 128 + h0 + c) * N + i] = a[c];
    }
}

// ---------------------------------------------------------------------------
// Kernel 2: 32x64 pair tile per block (1152 blocks), 2x4 pairs per thread.
// Inner loop in float2 packed form -> v_pk_fma_f32.
// ---------------------------------------------------------------------------
__global__ __launch_bounds__(256) void k2_main(
    const float* __restrict__ P, int nkc,
    const float* __restrict__ W1, const float* __restrict__ W2,
    const float* __restrict__ b2, const float* __restrict__ pos,
    const float* __restrict__ ppos, float* __restrict__ out)
{
    __shared__ float As[64][32];   // [h][i_local]
    __shared__ f4 Bs[64][16];      // [h][j_local/4]
    __shared__ float w3s[64];
    __shared__ f4 W2s[64];
    __shared__ float pis[32][3], vis[32][3], pjs[64][3], vjs[64][3];

    const int tid = threadIdx.x;
    const int i0 = blockIdx.y * 32;
    const int j0 = blockIdx.x * 64;

    // stage A tile: 64h x 32i = 512 f4 -> 2 per thread
#pragma unroll
    for (int g = 0; g < 2; ++g) {
        int f = g * 256 + tid;
        int h = f >> 3, c = f & 7;
        f4 s = {0.f, 0.f, 0.f, 0.f};
        for (int kc = 0; kc < nkc; ++kc)
            s += *(const f4*)&P[(size_t)(kc * 128 + h) * N + i0 + c * 4];
        *(f4*)&As[h][c * 4] = s;
    }
    // stage B tile: 64h x 64j = 1024 f4 -> 4 per thread
#pragma unroll
    for (int g = 0; g < 4; ++g) {
        int f = g * 256 + tid;
        int h = f >> 4, c = f & 15;
        f4 s = {0.f, 0.f, 0.f, 0.f};
        for (int kc = 0; kc < nkc; ++kc)
            s += *(const f4*)&P[(size_t)(kc * 128 + 64 + h) * N + j0 + c * 4];
        Bs[h][c] = s;
    }
    if (tid < 64) {
        w3s[tid] = W1[(size_t)(2 * D + 3) * H + tid];
        W2s[tid] = *(const f4*)&W2[tid * 4];
        int j = j0 + tid;
        float px = pos[3 * j], py = pos[3 * j + 1], pz = pos[3 * j + 2];
        pjs[tid][0] = px; pjs[tid][1] = py; pjs[tid][2] = pz;
        vjs[tid][0] = px - ppos[3 * j];
        vjs[tid][1] = py - ppos[3 * j + 1];
        vjs[tid][2] = pz - ppos[3 * j + 2];
    } else if (tid < 96) {
        int t = tid - 64;
        int i = i0 + t;
        float px = pos[3 * i], py = pos[3 * i + 1], pz = pos[3 * i + 2];
        pis[t][0] = px; pis[t][1] = py; pis[t][2] = pz;
        vis[t][0] = px - ppos[3 * i];
        vis[t][1] = py - ppos[3 * i + 1];
        vis[t][2] = pz - ppos[3 * i + 2];
    }
    __syncthreads();

    const int tx = tid & 15;   // j: tx*4 + 0..3
    const int ty = tid >> 4;   // i: ty*2 + 0..1

    // pair distances, numpy op order (threshold-sensitive)
    float dist[2][4];
    {
#pragma clang fp contract(off)
#pragma unroll
        for (int a = 0; a < 2; ++a) {
#pragma unroll
            for (int b = 0; b < 4; ++b) {
                int il = ty * 2 + a, jl = tx * 4 + b;
                float dx = pjs[jl][0] - pis[il][0];
                float dy = pjs[jl][1] - pis[il][1];
                float dz = pjs[jl][2] - pis[il][2];
                float s = dx * dx;
                s = s + dy * dy;
                s = s + dz * dz;
                dist[a][b] = sqrtf(s);
            }
        }
    }

    f2 d2[2][2];
#pragma unroll
    for (int a = 0; a < 2; ++a)
#pragma unroll
        for (int p = 0; p < 2; ++p)
            d2[a][p] = (f2){dist[a][2 * p], dist[a][2 * p + 1]};

    f2 acc[2][2][4];   // [a][jpair][logit]
#pragma unroll
    for (int a = 0; a < 2; ++a)
#pragma unroll
        for (int p = 0; p < 2; ++p)
#pragma unroll
            for (int l = 0; l < 4; ++l)
                acc[a][p][l] = (f2){0.f, 0.f};

#pragma unroll 8
    for (int h = 0; h < 64; ++h) {
        f2 Ai = *(const f2*)&As[h][ty * 2];
        f4 B4 = Bs[h][tx];
        float w3h = w3s[h];
        f4 w2r = W2s[h];
        f2 w3v = (f2){w3h, w3h};
        f2 wl0 = (f2){w2r.x, w2r.x};
        f2 wl1 = (f2){w2r.y, w2r.y};
        f2 wl2 = (f2){w2r.z, w2r.z};
        f2 wl3 = (f2){w2r.w, w2r.w};
#pragma unroll
        for (int a = 0; a < 2; ++a) {
            f2 Aa = (f2){Ai[a], Ai[a]};
#pragma unroll
            for (int p = 0; p < 2; ++p) {
                f2 Bp = (f2){B4[2 * p], B4[2 * p + 1]};
                f2 pre = Aa + Bp;
                f2 hid = __builtin_elementwise_fma(d2[a][p], w3v, pre);
                hid = __builtin_elementwise_max(hid, (f2){0.f, 0.f});
                acc[a][p][0] = __builtin_elementwise_fma(hid, wl0, acc[a][p][0]);
                acc[a][p][1] = __builtin_elementwise_fma(hid, wl1, acc[a][p][1]);
                acc[a][p][2] = __builtin_elementwise_fma(hid, wl2, acc[a][p][2]);
                acc[a][p][3] = __builtin_elementwise_fma(hid, wl3, acc[a][p][3]);
            }
        }
    }

    const f4 B2v = *(const f4*)b2;

#pragma unroll
    for (int a = 0; a < 2; ++a) {
        int il = ty * 2 + a;
        int i = i0 + il;
        f4 rt4, cf4, vl4;
#pragma unroll
        for (int b = 0; b < 4; ++b) {
            int jl = tx * 4 + b;
            int j = j0 + jl;
            int p = b >> 1, ln = b & 1;
            float dd = dist[a][b];
            float dy, closing;
            {
#pragma clang fp contract(off)
                float dx = pjs[jl][0] - pis[il][0];
                dy       = pjs[jl][1] - pis[il][1];
                float dz = pjs[jl][2] - pis[il][2];
                float rvx = vjs[jl][0] - vis[il][0];
                float rvy = vjs[jl][1] - vis[il][1];
                float rvz = vjs[jl][2] - vis[il][2];
                float dot = dx * rvx;
                dot = dot + dy * rvy;
                dot = dot + dz * rvz;
                closing = -dot / fmaxf(dd, 1e-6f);
            }
            float l0 = acc[a][p][0][ln] + B2v.x;
            float l1 = acc[a][p][1][ln] + B2v.y;
            float l2 = acc[a][p][2][ln] + B2v.z;
            float l3 = acc[a][p][3][ln] + B2v.w;
            float mx = l0; int bidx = 0;
            if (l1 > mx) { mx = l1; bidx = 1; }
            if (l2 > mx) { mx = l2; bidx = 2; }
            if (l3 > mx) { mx = l3; bidx = 3; }
            float s = expf(l0 - mx);
            s += expf(l1 - mx);
            s += expf(l2 - mx);
            s += expf(l3 - mx);
            float conf = 1.0f / s;   // == max softmax prob

            bool near = dd < 0.25f;
            bool appr = !near && (closing > 0.05f);
            bool flee = !near && !appr && (closing < -0.05f);
            bool above = !near && !appr && !flee && (fabsf(dy) > 0.3f) && (dd < 0.5f);
            int rt = near ? 0 : appr ? 1 : flee ? 2 : above ? 3 : bidx;
            float co = near  ? fmaxf(conf, 0.8f)
                     : appr  ? fmaxf(conf, 0.6f)
                     : flee  ? fmaxf(conf, 0.6f)
                     : above ? fmaxf(conf, 0.5f)
                             : conf;
            float vd = ((j > i) && (co > 0.3f)) ? 1.0f : 0.0f;
            rt4[b] = (float)rt;
            cf4[b] = co;
            vl4[b] = vd;
        }
        int col = j0 + tx * 4;
        *(f4*)&out[(size_t)i * N + col]                  = rt4;
        *(f4*)&out[(size_t)NN + (size_t)i * N + col]     = cf4;
        *(f4*)&out[(size_t)2 * NN + (size_t)i * N + col] = vl4;
    }
}

extern "C" void kernel_launch(void* const* d_in, const int* in_sizes, int n_in,
                              void* d_out, int out_size, void* d_ws, size_t ws_size,
                              hipStream_t stream)
{
    const float* E    = (const float*)d_in[0];   // N x 768
    const float* pos  = (const float*)d_in[1];   // N x 3
    const float* ppos = (const float*)d_in[2];   // N x 3
    const float* W1   = (const float*)d_in[3];   // 1544 x 64
    const float* b1   = (const float*)d_in[4];   // 64
    const float* W2   = (const float*)d_in[5];   // 64 x 4
    const float* b2   = (const float*)d_in[6];   // 4
    float* out = (float*)d_out;
    float* P   = (float*)d_ws;

    int nkc = (ws_size >= (size_t)4 * 128 * N * 4) ? 4 : 1;
    int KC  = D / nkc;

    dim3 g1(N / 16, nkc);
    k1_gemm<<<g1, 256, 0, stream>>>(E, pos, ppos, W1, b1, P, KC);

    dim3 g2(N / 64, N / 32);
    k2_main<<<g2, 256, 0, stream>>>(P, nkc, W1, W2, b2, pos, ppos, out);
}